// Round 14
// baseline (261.508 us; speedup 1.0000x reference)
//
#include <hip/hip_runtime.h>
#include <stdint.h>

#define BTOT   4096
#define NGRP   8
#define DMODEL 1024
#define HIDDEN 2048
#define ABIN   256

typedef short bf16x8 __attribute__((ext_vector_type(8)));
typedef float f32x4  __attribute__((ext_vector_type(4)));

__device__ __forceinline__ ushort f2bf(float f) {
    union { float f; uint32_t u; } v; v.f = f;
    return (ushort)((v.u + 0x7FFFu + ((v.u >> 16) & 1u)) >> 16);
}

__device__ __forceinline__ void gl_lds16(const ushort* g, ushort* l) {
    __builtin_amdgcn_global_load_lds(
        (const __attribute__((address_space(1))) uint32_t*)g,
        (__attribute__((address_space(3))) uint32_t*)l,
        16, 0, 0);
}

// ---- fused prep: transpose W1,W2 (64k x 128n vectorized tiles) + convert x ----
#define W1_TILES ((DMODEL / 64) * (HIDDEN / 128))   // 256
#define W2_TILES ((HIDDEN / 64) * (ABIN / 128))     // 64
#define TP_BLKS  (NGRP * (W1_TILES + W2_TILES))     // 2560
__global__ void prep(const float* __restrict__ W1, ushort* __restrict__ W1t,
                     const float* __restrict__ W2, ushort* __restrict__ W2t,
                     const float* __restrict__ x, ushort* __restrict__ xb,
                     int CH, int cb)
{
    const int t = threadIdx.x;
    if (blockIdx.x < TP_BLKS) {
        __shared__ float tl[64][133];
        const int n = blockIdx.x / (W1_TILES + W2_TILES);
        int bx      = blockIdx.x % (W1_TILES + W2_TILES);
        const float* W; ushort* Wt; int K, N, kt, nt;
        if (bx < W1_TILES) {
            W = W1; Wt = W1t; K = DMODEL; N = HIDDEN;
            kt = bx / (HIDDEN / 128); nt = bx % (HIDDEN / 128);
        } else {
            bx -= W1_TILES;
            W = W2; Wt = W2t; K = HIDDEN; N = ABIN;
            kt = bx / (ABIN / 128); nt = bx % (ABIN / 128);
        }
        const float* Wn  = W  + (size_t)n * K * N;
        ushort*      Wtn = Wt + (size_t)n * N * K;
#pragma unroll
        for (int i = 0; i < 8; i++) {
            const int idx = i * 256 + t;
            const int row = idx >> 5, c4 = (idx & 31) << 2;
            *(float4*)&tl[row][c4] =
                *(const float4*)(Wn + (size_t)(kt * 64 + row) * N + nt * 128 + c4);
        }
        __syncthreads();
#pragma unroll
        for (int j = 0; j < 4; j++) {
            const int oidx = j * 256 + t;
            const int orow = oidx >> 3, og = (oidx & 7) << 3;
            bf16x8 p;
#pragma unroll
            for (int e = 0; e < 8; e++) p[e] = (short)f2bf(tl[og + e][orow]);
            *(bf16x8*)(Wtn + (size_t)(nt * 128 + orow) * K + kt * 64 + og) = p;
        }
    } else {
        const int flat = (blockIdx.x - TP_BLKS) * 256 + t;
        const int d8 = flat & 127;
        const int rem = flat >> 7;
        const int n = rem & 7;
        const int r = rem >> 3;
        const float* src = x + ((size_t)(cb + r) * NGRP + n) * DMODEL + d8 * 8;
        float4 v0 = *(const float4*)(src);
        float4 v1 = *(const float4*)(src + 4);
        bf16x8 p;
        p[0] = (short)f2bf(v0.x); p[1] = (short)f2bf(v0.y);
        p[2] = (short)f2bf(v0.z); p[3] = (short)f2bf(v0.w);
        p[4] = (short)f2bf(v1.x); p[5] = (short)f2bf(v1.y);
        p[6] = (short)f2bf(v1.z); p[7] = (short)f2bf(v1.w);
        *(bf16x8*)(xb + ((size_t)n * CH + r) * DMODEL + d8 * 8) = p;
    }
}

// ---- x-only conversion (chunks after the first, if CH < BTOT) ----
__global__ void conv_x(const float* __restrict__ x, ushort* __restrict__ xb,
                       int CH, int cb)
{
    const int flat = blockIdx.x * 256 + threadIdx.x;
    const int d8 = flat & 127;
    const int rem = flat >> 7;
    const int n = rem & 7;
    const int r = rem >> 3;
    const float* src = x + ((size_t)(cb + r) * NGRP + n) * DMODEL + d8 * 8;
    float4 v0 = *(const float4*)(src);
    float4 v1 = *(const float4*)(src + 4);
    bf16x8 p;
    p[0] = (short)f2bf(v0.x); p[1] = (short)f2bf(v0.y);
    p[2] = (short)f2bf(v0.z); p[3] = (short)f2bf(v0.w);
    p[4] = (short)f2bf(v1.x); p[5] = (short)f2bf(v1.y);
    p[6] = (short)f2bf(v1.z); p[7] = (short)f2bf(v1.w);
    *(bf16x8*)(xb + ((size_t)n * CH + r) * DMODEL + d8 * 8) = p;
}

// region(buf,op,half,ks): 128 rows x 32 k bf16 = 8 KiB, swizzled granules
#define REGN(buf,op,half,ks) (sm + ((((buf)*2+(op))*2+(half))*2+(ks))*4096)

template<int MH>
__device__ __forceinline__ void mma_q(f32x4 (&acc)[8][4], const bf16x8 (&af)[4],
                                      const bf16x8 (&bv)[4])
{
#pragma unroll
    for (int m4 = 0; m4 < 4; ++m4)
#pragma unroll
        for (int nf = 0; nf < 4; ++nf)
            acc[MH * 4 + m4][nf] = __builtin_amdgcn_mfma_f32_16x16x32_bf16(
                af[m4], bv[nf], acc[MH * 4 + m4][nf], 0, 0, 0);
}

// ---- 256x256 8-phase GEMM1 with 1-deep fragment pipeline (R4, frozen) ----
__global__ __launch_bounds__(512, 2)
void gemm8_1(const ushort* __restrict__ A, const ushort* __restrict__ Bt,
             const float* __restrict__ bias, ushort* __restrict__ h, int CH)
{
    constexpr int K = DMODEL, NDIM = HIDDEN, KT = K / 64;
    const int MT = CH >> 8, NT = NDIM >> 8;     // NT = 8
    extern __shared__ ushort sm[];

    const int nwg = gridDim.x;
    const int bid = blockIdx.x;
    const int swz = (bid & 7) * (nwg >> 3) + (bid >> 3);
    const int n   = swz / (MT * NT);
    const int rem = swz - n * (MT * NT);
    const int mt  = rem / NT;
    const int nt  = rem - mt * NT;

    const int tid = threadIdx.x;
    const int l = tid & 63, wid = tid >> 6;
    const int wr = wid >> 2, wc = wid & 3, wc2 = wc >> 1;
    const int lq = l >> 4, lr = l & 15;

    const ushort* Ab = A  + ((size_t)n * CH   + (size_t)mt * 256) * K;
    const ushort* Bb = Bt + ((size_t)n * NDIM + (size_t)nt * 256) * K;

    const int srow = tid >> 2;
    const int sseg = (tid & 3) ^ ((tid >> 3) & 3);

    auto stageA = [&](int b, int T, int ks) {
        const size_t kofs = (size_t)T * 64 + ks * 32 + sseg * 8;
        gl_lds16(Ab + (size_t)srow * K + kofs,         REGN(b, 0, 0, ks) + tid * 8);
        gl_lds16(Ab + (size_t)(128 + srow) * K + kofs, REGN(b, 0, 1, ks) + tid * 8);
    };
    auto stageB = [&](int b, int T, int ks) {
        const size_t kofs = (size_t)T * 64 + ks * 32 + sseg * 8;
        gl_lds16(Bb + (size_t)srow * K + kofs,         REGN(b, 1, 0, ks) + tid * 8);
        gl_lds16(Bb + (size_t)(128 + srow) * K + kofs, REGN(b, 1, 1, ks) + tid * 8);
    };
    auto ldA = [&](bf16x8 (&af)[4], int b, int kk, int mh) {
#pragma unroll
        for (int m4 = 0; m4 < 4; ++m4) {
            const int rh = mh * 64 + m4 * 16 + lr;
            af[m4] = *(const bf16x8*)(REGN(b, 0, wr, kk) + rh * 32 + (lq ^ ((rh >> 1) & 3)) * 8);
        }
    };
    auto ldB = [&](bf16x8 (&bv)[4], int b, int kk) {
#pragma unroll
        for (int nf = 0; nf < 4; ++nf) {
            const int rb = (wc & 1) * 64 + nf * 16 + lr;
            bv[nf] = *(const bf16x8*)(REGN(b, 1, wc2, kk) + rb * 32 + (lq ^ ((rb >> 1) & 3)) * 8);
        }
    };

    f32x4 acc[8][4];
#pragma unroll
    for (int i = 0; i < 8; ++i)
#pragma unroll
        for (int j = 0; j < 4; ++j) acc[i][j] = (f32x4){0.f, 0.f, 0.f, 0.f};

    stageA(0, 0, 0); stageB(0, 0, 0); stageA(0, 0, 1); stageB(0, 0, 1);
    asm volatile("s_waitcnt vmcnt(4)" ::: "memory");
    __builtin_amdgcn_s_barrier();

    bf16x8 aX[4], aY[4], bv0[4], bv1[4];
    ldA(aX, 0, 0, 0); ldB(bv0, 0, 0);

    for (int g = 0; g < KT; ++g) {
        const int c = g & 1;
        const bool ns = (g + 1 < KT);

        ldA(aY, c, 0, 1);
        if (ns) stageA(c ^ 1, g + 1, 0);
        asm volatile("s_waitcnt lgkmcnt(4)" ::: "memory");
        __builtin_amdgcn_sched_barrier(0);
        __builtin_amdgcn_s_setprio(1);
        mma_q<0>(acc, aX, bv0);
        __builtin_amdgcn_s_setprio(0);
        if (ns) asm volatile("s_waitcnt vmcnt(2)" ::: "memory");
        else    asm volatile("s_waitcnt vmcnt(0)" ::: "memory");
        __builtin_amdgcn_s_barrier();

        ldA(aX, c, 1, 0); ldB(bv1, c, 1);
        if (ns) stageB(c ^ 1, g + 1, 0);
        asm volatile("s_waitcnt lgkmcnt(8)" ::: "memory");
        __builtin_amdgcn_sched_barrier(0);
        __builtin_amdgcn_s_setprio(1);
        mma_q<1>(acc, aY, bv0);
        __builtin_amdgcn_s_setprio(0);
        __builtin_amdgcn_s_barrier();

        ldA(aY, c, 1, 1);
        if (ns) stageA(c ^ 1, g + 1, 1);
        asm volatile("s_waitcnt lgkmcnt(4)" ::: "memory");
        __builtin_amdgcn_sched_barrier(0);
        __builtin_amdgcn_s_setprio(1);
        mma_q<0>(acc, aX, bv1);
        __builtin_amdgcn_s_setprio(0);
        __builtin_amdgcn_s_barrier();

        if (ns) stageB(c ^ 1, g + 1, 1);
        asm volatile("s_waitcnt lgkmcnt(0)" ::: "memory");
        __builtin_amdgcn_sched_barrier(0);
        __builtin_amdgcn_s_setprio(1);
        mma_q<1>(acc, aY, bv1);
        __builtin_amdgcn_s_setprio(0);
        if (ns) asm volatile("s_waitcnt vmcnt(4)" ::: "memory");
        __builtin_amdgcn_s_barrier();
        if (ns) { ldA(aX, c ^ 1, 0, 0); ldB(bv0, c ^ 1, 0); }
    }

    __builtin_amdgcn_sched_barrier(0);

    float bias4[4];
#pragma unroll
    for (int nf = 0; nf < 4; ++nf)
        bias4[nf] = bias[(size_t)n * NDIM + nt * 256 + wc * 64 + nf * 16 + lr];
#pragma unroll
    for (int m = 0; m < 8; ++m) {
#pragma unroll
        for (int r = 0; r < 4; ++r) {
            const int row = mt * 256 + wr * 128 + m * 16 + lq * 4 + r;
            ushort* dst = h + ((size_t)n * CH + row) * HIDDEN + nt * 256 + wc * 64 + lr;
#pragma unroll
            for (int nf = 0; nf < 4; ++nf)
                dst[nf * 16] = f2bf(fmaxf(acc[m][nf][r] + bias4[nf], 0.f));
        }
    }
}

// ---- GEMM2 64x256, BK=32, dbuf 40 KB -> 4 blocks/CU, counted vmcnt ----
// swizzle: store seg=(flat&3)^((row>>1)&3); read slot lq^((row>>1)&3)
// bank audit: collisions only at drow=8 -> exactly 2 lanes/bank (free)
__global__ __launch_bounds__(256, 4)
void gemm2w(const ushort* __restrict__ A, const ushort* __restrict__ Bt,
            const float* __restrict__ bias, float* __restrict__ outp,
            int CH, int cb)
{
    constexpr int K = HIDDEN, BK = 32, KT = K / BK;   // 64 k-tiles
    constexpr int BUFSZ = (64 + 256) * BK;            // 10240 ushorts = 20 KB
    extern __shared__ ushort sm2[];

    const int n  = blockIdx.y;
    const int mt = blockIdx.x;

    const ushort* Ab = A  + ((size_t)n * CH + mt * 64) * K;
    const ushort* Bb = Bt + (size_t)n * ABIN * K;

    const int t = threadIdx.x, l = t & 63, w = t >> 6;
    const int wr = w >> 1, wc = w & 1;      // 2M x 2N: wave = 32 rows x 128 cols
    const int lq = l >> 4, lr = l & 15;

    auto stage = [&](int b, int ki) {       // 5 gl_lds per thread
        ushort* As = sm2 + b * BUFSZ;
        ushort* Bs = As + 64 * BK;
        const ushort* Ak = Ab + ki * BK;
        const ushort* Bk = Bb + ki * BK;
        {
            const int row = t >> 2;
            const int seg = (t & 3) ^ ((row >> 1) & 3);
            gl_lds16(Ak + (size_t)row * K + seg * 8, As + t * 8);
        }
#pragma unroll
        for (int i = 0; i < 4; i++) {
            const int flat = t + 256 * i;
            const int row = flat >> 2;
            const int seg = (flat & 3) ^ ((row >> 1) & 3);
            gl_lds16(Bk + (size_t)row * K + seg * 8, Bs + flat * 8);
        }
    };

    f32x4 acc[2][8];
#pragma unroll
    for (int i = 0; i < 2; i++)
#pragma unroll
        for (int j = 0; j < 8; j++) acc[i][j] = (f32x4){0.f, 0.f, 0.f, 0.f};

    stage(0, 0);                            // prologue: 5 loads in flight

    for (int ki = 0; ki < KT; ++ki) {
        const int c = ki & 1;
        if (ki + 1 < KT) {
            stage(c ^ 1, ki + 1);           // outstanding 10
            asm volatile("s_waitcnt vmcnt(5)" ::: "memory"); // tile ki landed
        } else {
            asm volatile("s_waitcnt vmcnt(0)" ::: "memory");
        }
        __builtin_amdgcn_s_barrier();
        __builtin_amdgcn_sched_barrier(0);

        const ushort* As = sm2 + c * BUFSZ;
        const ushort* Bs = As + 64 * BK;
        bf16x8 af[2], bf[8];
#pragma unroll
        for (int m = 0; m < 2; m++) {
            const int row = wr * 32 + m * 16 + lr;
            af[m] = *(const bf16x8*)&As[row * BK + (lq ^ ((row >> 1) & 3)) * 8];
        }
#pragma unroll
        for (int nf = 0; nf < 8; nf++) {
            const int row = wc * 128 + nf * 16 + lr;
            bf[nf] = *(const bf16x8*)&Bs[row * BK + (lq ^ ((row >> 1) & 3)) * 8];
        }
#pragma unroll
        for (int m = 0; m < 2; m++)
#pragma unroll
            for (int nf = 0; nf < 8; nf++)
                acc[m][nf] = __builtin_amdgcn_mfma_f32_16x16x32_bf16(af[m], bf[nf], acc[m][nf], 0, 0, 0);
        __builtin_amdgcn_s_barrier();       // WAR: buf c reads done before ki+1 stage
    }

    float bias8[8];
#pragma unroll
    for (int nf = 0; nf < 8; nf++)
        bias8[nf] = bias[(size_t)n * ABIN + wc * 128 + nf * 16 + lr];
#pragma unroll
    for (int m = 0; m < 2; m++) {
#pragma unroll
        for (int r = 0; r < 4; r++) {
            const int row = mt * 64 + wr * 32 + m * 16 + lq * 4 + r;
            float* dst = outp + ((size_t)(cb + row) * NGRP + n) * ABIN + wc * 128 + lr;
#pragma unroll
            for (int nf = 0; nf < 8; nf++)
                dst[nf * 16] = acc[m][nf][r] + bias8[nf];
        }
    }
}

extern "C" void kernel_launch(void* const* d_in, const int* in_sizes, int n_in,
                              void* d_out, int out_size, void* d_ws, size_t ws_size,
                              hipStream_t stream)
{
    const float* x  = (const float*)d_in[0];
    const float* W1 = (const float*)d_in[1];
    const float* b1 = (const float*)d_in[2];
    const float* W2 = (const float*)d_in[3];
    const float* b2 = (const float*)d_in[4];

    hipFuncSetAttribute((const void*)gemm8_1,
                        hipFuncAttributeMaxDynamicSharedMemorySize, 131072);
    hipFuncSetAttribute((const void*)gemm2w,
                        hipFuncAttributeMaxDynamicSharedMemorySize, 40960);

    ushort* W1t = (ushort*)d_ws;                              // [8][2048][1024]
    ushort* W2t = W1t + (size_t)NGRP * HIDDEN * DMODEL;       // [8][256][2048]
    ushort* xb  = W2t + (size_t)NGRP * ABIN * HIDDEN;
    const size_t fixed = ((size_t)NGRP * HIDDEN * DMODEL + (size_t)NGRP * ABIN * HIDDEN) * 2;

    int CH = 4096;
    while (CH > 256 && fixed + (size_t)CH * (NGRP * (DMODEL + HIDDEN) * 2) > ws_size) CH >>= 1;
    ushort* h = xb + (size_t)NGRP * CH * DMODEL;

    // chunk 0: fused transpose(W1,W2) + conv(x chunk 0)
    prep<<<TP_BLKS + CH * 4, 256, 0, stream>>>(W1, W1t, W2, W2t, x, xb, CH, 0);

    for (int cb = 0; cb < BTOT; cb += CH) {
        if (cb > 0)
            conv_x<<<CH * 4, 256, 0, stream>>>(x, xb, CH, cb);
        const int g1 = NGRP * (CH / 256) * (HIDDEN / 256);
        gemm8_1<<<g1, 512, 131072, stream>>>(xb, W1t, b1, h, CH);
        dim3 g2(CH / 64, NGRP);
        gemm2w<<<g2, 256, 40960, stream>>>(h, W2t, b2, (float*)d_out, CH, cb);
    }
}

// Round 15
// 248.423 us; speedup vs baseline: 1.0527x; 1.0527x over previous
//
#include <hip/hip_runtime.h>
#include <stdint.h>

#define BTOT   4096
#define NGRP   8
#define DMODEL 1024
#define HIDDEN 2048
#define ABIN   256

typedef short bf16x8 __attribute__((ext_vector_type(8)));
typedef float f32x4  __attribute__((ext_vector_type(4)));

__device__ __forceinline__ ushort f2bf(float f) {
    union { float f; uint32_t u; } v; v.f = f;
    return (ushort)((v.u + 0x7FFFu + ((v.u >> 16) & 1u)) >> 16);
}

__device__ __forceinline__ void gl_lds16(const ushort* g, ushort* l) {
    __builtin_amdgcn_global_load_lds(
        (const __attribute__((address_space(1))) uint32_t*)g,
        (__attribute__((address_space(3))) uint32_t*)l,
        16, 0, 0);
}

// ---- fused prep: transpose W1,W2 (64k x 128n vectorized tiles) + convert x ----
#define W1_TILES ((DMODEL / 64) * (HIDDEN / 128))   // 256
#define W2_TILES ((HIDDEN / 64) * (ABIN / 128))     // 64
#define TP_BLKS  (NGRP * (W1_TILES + W2_TILES))     // 2560
__global__ void prep(const float* __restrict__ W1, ushort* __restrict__ W1t,
                     const float* __restrict__ W2, ushort* __restrict__ W2t,
                     const float* __restrict__ x, ushort* __restrict__ xb,
                     int CH, int cb)
{
    const int t = threadIdx.x;
    if (blockIdx.x < TP_BLKS) {
        __shared__ float tl[64][133];
        const int n = blockIdx.x / (W1_TILES + W2_TILES);
        int bx      = blockIdx.x % (W1_TILES + W2_TILES);
        const float* W; ushort* Wt; int K, N, kt, nt;
        if (bx < W1_TILES) {
            W = W1; Wt = W1t; K = DMODEL; N = HIDDEN;
            kt = bx / (HIDDEN / 128); nt = bx % (HIDDEN / 128);
        } else {
            bx -= W1_TILES;
            W = W2; Wt = W2t; K = HIDDEN; N = ABIN;
            kt = bx / (ABIN / 128); nt = bx % (ABIN / 128);
        }
        const float* Wn  = W  + (size_t)n * K * N;
        ushort*      Wtn = Wt + (size_t)n * N * K;
#pragma unroll
        for (int i = 0; i < 8; i++) {
            const int idx = i * 256 + t;
            const int row = idx >> 5, c4 = (idx & 31) << 2;
            *(float4*)&tl[row][c4] =
                *(const float4*)(Wn + (size_t)(kt * 64 + row) * N + nt * 128 + c4);
        }
        __syncthreads();
#pragma unroll
        for (int j = 0; j < 4; j++) {
            const int oidx = j * 256 + t;
            const int orow = oidx >> 3, og = (oidx & 7) << 3;
            bf16x8 p;
#pragma unroll
            for (int e = 0; e < 8; e++) p[e] = (short)f2bf(tl[og + e][orow]);
            *(bf16x8*)(Wtn + (size_t)(nt * 128 + orow) * K + kt * 64 + og) = p;
        }
    } else {
        const int flat = (blockIdx.x - TP_BLKS) * 256 + t;
        const int d8 = flat & 127;
        const int rem = flat >> 7;
        const int n = rem & 7;
        const int r = rem >> 3;
        const float* src = x + ((size_t)(cb + r) * NGRP + n) * DMODEL + d8 * 8;
        float4 v0 = *(const float4*)(src);
        float4 v1 = *(const float4*)(src + 4);
        bf16x8 p;
        p[0] = (short)f2bf(v0.x); p[1] = (short)f2bf(v0.y);
        p[2] = (short)f2bf(v0.z); p[3] = (short)f2bf(v0.w);
        p[4] = (short)f2bf(v1.x); p[5] = (short)f2bf(v1.y);
        p[6] = (short)f2bf(v1.z); p[7] = (short)f2bf(v1.w);
        *(bf16x8*)(xb + ((size_t)n * CH + r) * DMODEL + d8 * 8) = p;
    }
}

// ---- x-only conversion (chunks after the first, if CH < BTOT) ----
__global__ void conv_x(const float* __restrict__ x, ushort* __restrict__ xb,
                       int CH, int cb)
{
    const int flat = blockIdx.x * 256 + threadIdx.x;
    const int d8 = flat & 127;
    const int rem = flat >> 7;
    const int n = rem & 7;
    const int r = rem >> 3;
    const float* src = x + ((size_t)(cb + r) * NGRP + n) * DMODEL + d8 * 8;
    float4 v0 = *(const float4*)(src);
    float4 v1 = *(const float4*)(src + 4);
    bf16x8 p;
    p[0] = (short)f2bf(v0.x); p[1] = (short)f2bf(v0.y);
    p[2] = (short)f2bf(v0.z); p[3] = (short)f2bf(v0.w);
    p[4] = (short)f2bf(v1.x); p[5] = (short)f2bf(v1.y);
    p[6] = (short)f2bf(v1.z); p[7] = (short)f2bf(v1.w);
    *(bf16x8*)(xb + ((size_t)n * CH + r) * DMODEL + d8 * 8) = p;
}

// region(buf,op,half,ks): 128 rows x 32 k bf16 = 8 KiB, swizzled granules
#define REGN(buf,op,half,ks) (sm + ((((buf)*2+(op))*2+(half))*2+(ks))*4096)

template<int MH>
__device__ __forceinline__ void mma_q(f32x4 (&acc)[8][4], const bf16x8 (&af)[4],
                                      const bf16x8 (&bv)[4])
{
#pragma unroll
    for (int m4 = 0; m4 < 4; ++m4)
#pragma unroll
        for (int nf = 0; nf < 4; ++nf)
            acc[MH * 4 + m4][nf] = __builtin_amdgcn_mfma_f32_16x16x32_bf16(
                af[m4], bv[nf], acc[MH * 4 + m4][nf], 0, 0, 0);
}

// ---- 256x256 8-phase GEMM1 with 1-deep fragment pipeline (R4, frozen) ----
__global__ __launch_bounds__(512, 2)
void gemm8_1(const ushort* __restrict__ A, const ushort* __restrict__ Bt,
             const float* __restrict__ bias, ushort* __restrict__ h, int CH)
{
    constexpr int K = DMODEL, NDIM = HIDDEN, KT = K / 64;
    const int MT = CH >> 8, NT = NDIM >> 8;     // NT = 8
    extern __shared__ ushort sm[];

    const int nwg = gridDim.x;
    const int bid = blockIdx.x;
    const int swz = (bid & 7) * (nwg >> 3) + (bid >> 3);
    const int n   = swz / (MT * NT);
    const int rem = swz - n * (MT * NT);
    const int mt  = rem / NT;
    const int nt  = rem - mt * NT;

    const int tid = threadIdx.x;
    const int l = tid & 63, wid = tid >> 6;
    const int wr = wid >> 2, wc = wid & 3, wc2 = wc >> 1;
    const int lq = l >> 4, lr = l & 15;

    const ushort* Ab = A  + ((size_t)n * CH   + (size_t)mt * 256) * K;
    const ushort* Bb = Bt + ((size_t)n * NDIM + (size_t)nt * 256) * K;

    const int srow = tid >> 2;
    const int sseg = (tid & 3) ^ ((tid >> 3) & 3);

    auto stageA = [&](int b, int T, int ks) {
        const size_t kofs = (size_t)T * 64 + ks * 32 + sseg * 8;
        gl_lds16(Ab + (size_t)srow * K + kofs,         REGN(b, 0, 0, ks) + tid * 8);
        gl_lds16(Ab + (size_t)(128 + srow) * K + kofs, REGN(b, 0, 1, ks) + tid * 8);
    };
    auto stageB = [&](int b, int T, int ks) {
        const size_t kofs = (size_t)T * 64 + ks * 32 + sseg * 8;
        gl_lds16(Bb + (size_t)srow * K + kofs,         REGN(b, 1, 0, ks) + tid * 8);
        gl_lds16(Bb + (size_t)(128 + srow) * K + kofs, REGN(b, 1, 1, ks) + tid * 8);
    };
    auto ldA = [&](bf16x8 (&af)[4], int b, int kk, int mh) {
#pragma unroll
        for (int m4 = 0; m4 < 4; ++m4) {
            const int rh = mh * 64 + m4 * 16 + lr;
            af[m4] = *(const bf16x8*)(REGN(b, 0, wr, kk) + rh * 32 + (lq ^ ((rh >> 1) & 3)) * 8);
        }
    };
    auto ldB = [&](bf16x8 (&bv)[4], int b, int kk) {
#pragma unroll
        for (int nf = 0; nf < 4; ++nf) {
            const int rb = (wc & 1) * 64 + nf * 16 + lr;
            bv[nf] = *(const bf16x8*)(REGN(b, 1, wc2, kk) + rb * 32 + (lq ^ ((rb >> 1) & 3)) * 8);
        }
    };

    f32x4 acc[8][4];
#pragma unroll
    for (int i = 0; i < 8; ++i)
#pragma unroll
        for (int j = 0; j < 4; ++j) acc[i][j] = (f32x4){0.f, 0.f, 0.f, 0.f};

    stageA(0, 0, 0); stageB(0, 0, 0); stageA(0, 0, 1); stageB(0, 0, 1);
    asm volatile("s_waitcnt vmcnt(4)" ::: "memory");
    __builtin_amdgcn_s_barrier();

    bf16x8 aX[4], aY[4], bv0[4], bv1[4];
    ldA(aX, 0, 0, 0); ldB(bv0, 0, 0);

    for (int g = 0; g < KT; ++g) {
        const int c = g & 1;
        const bool ns = (g + 1 < KT);

        ldA(aY, c, 0, 1);
        if (ns) stageA(c ^ 1, g + 1, 0);
        asm volatile("s_waitcnt lgkmcnt(4)" ::: "memory");
        __builtin_amdgcn_sched_barrier(0);
        __builtin_amdgcn_s_setprio(1);
        mma_q<0>(acc, aX, bv0);
        __builtin_amdgcn_s_setprio(0);
        if (ns) asm volatile("s_waitcnt vmcnt(2)" ::: "memory");
        else    asm volatile("s_waitcnt vmcnt(0)" ::: "memory");
        __builtin_amdgcn_s_barrier();

        ldA(aX, c, 1, 0); ldB(bv1, c, 1);
        if (ns) stageB(c ^ 1, g + 1, 0);
        asm volatile("s_waitcnt lgkmcnt(8)" ::: "memory");
        __builtin_amdgcn_sched_barrier(0);
        __builtin_amdgcn_s_setprio(1);
        mma_q<1>(acc, aY, bv0);
        __builtin_amdgcn_s_setprio(0);
        __builtin_amdgcn_s_barrier();

        ldA(aY, c, 1, 1);
        if (ns) stageA(c ^ 1, g + 1, 1);
        asm volatile("s_waitcnt lgkmcnt(4)" ::: "memory");
        __builtin_amdgcn_sched_barrier(0);
        __builtin_amdgcn_s_setprio(1);
        mma_q<0>(acc, aX, bv1);
        __builtin_amdgcn_s_setprio(0);
        __builtin_amdgcn_s_barrier();

        if (ns) stageB(c ^ 1, g + 1, 1);
        asm volatile("s_waitcnt lgkmcnt(0)" ::: "memory");
        __builtin_amdgcn_sched_barrier(0);
        __builtin_amdgcn_s_setprio(1);
        mma_q<1>(acc, aY, bv1);
        __builtin_amdgcn_s_setprio(0);
        if (ns) asm volatile("s_waitcnt vmcnt(4)" ::: "memory");
        __builtin_amdgcn_s_barrier();
        if (ns) { ldA(aX, c ^ 1, 0, 0); ldB(bv0, c ^ 1, 0); }
    }

    __builtin_amdgcn_sched_barrier(0);

    float bias4[4];
#pragma unroll
    for (int nf = 0; nf < 4; ++nf)
        bias4[nf] = bias[(size_t)n * NDIM + nt * 256 + wc * 64 + nf * 16 + lr];
#pragma unroll
    for (int m = 0; m < 8; ++m) {
#pragma unroll
        for (int r = 0; r < 4; ++r) {
            const int row = mt * 256 + wr * 128 + m * 16 + lq * 4 + r;
            ushort* dst = h + ((size_t)n * CH + row) * HIDDEN + nt * 256 + wc * 64 + lr;
#pragma unroll
            for (int nf = 0; nf < 4; ++nf)
                dst[nf * 16] = f2bf(fmaxf(acc[m][nf][r] + bias4[nf], 0.f));
        }
    }
}

// ---- GEMM2 64x256 dbuf + counted vmcnt gate (R12 proven): out = h@W2t^T + b2 ----
__global__ __launch_bounds__(256, 2)
void gemm2w(const ushort* __restrict__ A, const ushort* __restrict__ Bt,
            const float* __restrict__ bias, float* __restrict__ outp,
            int CH, int cb)
{
    constexpr int K = HIDDEN, BK = 64, KT = K / BK;
    constexpr int BUFSZ = (64 + 256) * BK;
    extern __shared__ ushort sm2[];

    const int n  = blockIdx.y;
    const int mt = blockIdx.x;

    const ushort* Ab = A  + ((size_t)n * CH + mt * 64) * K;
    const ushort* Bb = Bt + (size_t)n * ABIN * K;

    const int t = threadIdx.x, l = t & 63, w = t >> 6;
    const int wr = w >> 1, wc = w & 1;
    const int lq = l >> 4, lr = l & 15;

    auto stage = [&](int b, int ki) {
        ushort* As = sm2 + b * BUFSZ;
        ushort* Bs = As + 64 * BK;
        const ushort* Ak = Ab + ki * BK;
        const ushort* Bk = Bb + ki * BK;
#pragma unroll
        for (int i = 0; i < 2; i++) {
            const int flat = t + 256 * i;
            const int row = flat >> 3;
            const int seg = (flat & 7) ^ (row & 7);
            gl_lds16(Ak + (size_t)row * K + seg * 8, As + flat * 8);
        }
#pragma unroll
        for (int i = 0; i < 8; i++) {
            const int flat = t + 256 * i;
            const int row = flat >> 3;
            const int seg = (flat & 7) ^ (row & 7);
            gl_lds16(Bk + (size_t)row * K + seg * 8, Bs + flat * 8);
        }
    };

    f32x4 acc[2][8];
#pragma unroll
    for (int i = 0; i < 2; i++)
#pragma unroll
        for (int j = 0; j < 8; j++) acc[i][j] = (f32x4){0.f, 0.f, 0.f, 0.f};

    stage(0, 0);

    for (int ki = 0; ki < KT; ++ki) {
        const int c = ki & 1;
        if (ki + 1 < KT) {
            stage(c ^ 1, ki + 1);
            asm volatile("s_waitcnt vmcnt(10)" ::: "memory");
        } else {
            asm volatile("s_waitcnt vmcnt(0)" ::: "memory");
        }
        __builtin_amdgcn_s_barrier();
        __builtin_amdgcn_sched_barrier(0);

        const ushort* As = sm2 + c * BUFSZ;
        const ushort* Bs = As + 64 * BK;
#pragma unroll
        for (int kk = 0; kk < 2; kk++) {
            bf16x8 af[2], bf[8];
#pragma unroll
            for (int m = 0; m < 2; m++) {
                const int row = wr * 32 + m * 16 + lr;
                af[m] = *(const bf16x8*)&As[row * BK + ((kk * 4 + lq) ^ (row & 7)) * 8];
            }
#pragma unroll
            for (int nf = 0; nf < 8; nf++) {
                const int row = wc * 128 + nf * 16 + lr;
                bf[nf] = *(const bf16x8*)&Bs[row * BK + ((kk * 4 + lq) ^ (row & 7)) * 8];
            }
#pragma unroll
            for (int m = 0; m < 2; m++)
#pragma unroll
                for (int nf = 0; nf < 8; nf++)
                    acc[m][nf] = __builtin_amdgcn_mfma_f32_16x16x32_bf16(af[m], bf[nf], acc[m][nf], 0, 0, 0);
        }
        __builtin_amdgcn_s_barrier();
    }

    float bias8[8];
#pragma unroll
    for (int nf = 0; nf < 8; nf++)
        bias8[nf] = bias[(size_t)n * ABIN + wc * 128 + nf * 16 + lr];
#pragma unroll
    for (int m = 0; m < 2; m++) {
#pragma unroll
        for (int r = 0; r < 4; r++) {
            const int row = mt * 64 + wr * 32 + m * 16 + lq * 4 + r;
            float* dst = outp + ((size_t)(cb + row) * NGRP + n) * ABIN + wc * 128 + lr;
#pragma unroll
            for (int nf = 0; nf < 8; nf++)
                dst[nf * 16] = acc[m][nf][r] + bias8[nf];
        }
    }
}

extern "C" void kernel_launch(void* const* d_in, const int* in_sizes, int n_in,
                              void* d_out, int out_size, void* d_ws, size_t ws_size,
                              hipStream_t stream)
{
    const float* x  = (const float*)d_in[0];
    const float* W1 = (const float*)d_in[1];
    const float* b1 = (const float*)d_in[2];
    const float* W2 = (const float*)d_in[3];
    const float* b2 = (const float*)d_in[4];

    hipFuncSetAttribute((const void*)gemm8_1,
                        hipFuncAttributeMaxDynamicSharedMemorySize, 131072);
    hipFuncSetAttribute((const void*)gemm2w,
                        hipFuncAttributeMaxDynamicSharedMemorySize, 81920);

    ushort* W1t = (ushort*)d_ws;                              // [8][2048][1024]
    ushort* W2t = W1t + (size_t)NGRP * HIDDEN * DMODEL;       // [8][256][2048]
    ushort* xb  = W2t + (size_t)NGRP * ABIN * HIDDEN;
    const size_t fixed = ((size_t)NGRP * HIDDEN * DMODEL + (size_t)NGRP * ABIN * HIDDEN) * 2;

    int CH = 4096;
    while (CH > 256 && fixed + (size_t)CH * (NGRP * (DMODEL + HIDDEN) * 2) > ws_size) CH >>= 1;
    ushort* h = xb + (size_t)NGRP * CH * DMODEL;

    // chunk 0: fused transpose(W1,W2) + conv(x chunk 0)
    prep<<<TP_BLKS + CH * 4, 256, 0, stream>>>(W1, W1t, W2, W2t, x, xb, CH, 0);

    for (int cb = 0; cb < BTOT; cb += CH) {
        if (cb > 0)
            conv_x<<<CH * 4, 256, 0, stream>>>(x, xb, CH, cb);
        const int g1 = NGRP * (CH / 256) * (HIDDEN / 256);
        gemm8_1<<<g1, 512, 131072, stream>>>(xb, W1t, b1, h, CH);
        dim3 g2(CH / 64, NGRP);
        gemm2w<<<g2, 256, 81920, stream>>>(h, W2t, b2, (float*)d_out, CH, cb);
    }
}

// Round 16
// 245.446 us; speedup vs baseline: 1.0654x; 1.0121x over previous
//
#include <hip/hip_runtime.h>
#include <stdint.h>

#define BTOT   4096
#define NGRP   8
#define DMODEL 1024
#define HIDDEN 2048
#define ABIN   256

typedef short bf16x8 __attribute__((ext_vector_type(8)));
typedef float f32x4  __attribute__((ext_vector_type(4)));

__device__ __forceinline__ ushort f2bf(float f) {
    union { float f; uint32_t u; } v; v.f = f;
    return (ushort)((v.u + 0x7FFFu + ((v.u >> 16) & 1u)) >> 16);
}

__device__ __forceinline__ void gl_lds16(const ushort* g, ushort* l) {
    __builtin_amdgcn_global_load_lds(
        (const __attribute__((address_space(1))) uint32_t*)g,
        (__attribute__((address_space(3))) uint32_t*)l,
        16, 0, 0);
}

// ---- fused prep: transpose W1,W2 (64k x 128n vectorized tiles) + convert x ----
#define W1_TILES ((DMODEL / 64) * (HIDDEN / 128))   // 256
#define W2_TILES ((HIDDEN / 64) * (ABIN / 128))     // 64
#define TP_BLKS  (NGRP * (W1_TILES + W2_TILES))     // 2560
__global__ void prep(const float* __restrict__ W1, ushort* __restrict__ W1t,
                     const float* __restrict__ W2, ushort* __restrict__ W2t,
                     const float* __restrict__ x, ushort* __restrict__ xb,
                     int CH, int cb)
{
    const int t = threadIdx.x;
    if (blockIdx.x < TP_BLKS) {
        __shared__ float tl[64][133];
        const int n = blockIdx.x / (W1_TILES + W2_TILES);
        int bx      = blockIdx.x % (W1_TILES + W2_TILES);
        const float* W; ushort* Wt; int K, N, kt, nt;
        if (bx < W1_TILES) {
            W = W1; Wt = W1t; K = DMODEL; N = HIDDEN;
            kt = bx / (HIDDEN / 128); nt = bx % (HIDDEN / 128);
        } else {
            bx -= W1_TILES;
            W = W2; Wt = W2t; K = HIDDEN; N = ABIN;
            kt = bx / (ABIN / 128); nt = bx % (ABIN / 128);
        }
        const float* Wn  = W  + (size_t)n * K * N;
        ushort*      Wtn = Wt + (size_t)n * N * K;
#pragma unroll
        for (int i = 0; i < 8; i++) {
            const int idx = i * 256 + t;
            const int row = idx >> 5, c4 = (idx & 31) << 2;
            *(float4*)&tl[row][c4] =
                *(const float4*)(Wn + (size_t)(kt * 64 + row) * N + nt * 128 + c4);
        }
        __syncthreads();
#pragma unroll
        for (int j = 0; j < 4; j++) {
            const int oidx = j * 256 + t;
            const int orow = oidx >> 3, og = (oidx & 7) << 3;
            bf16x8 p;
#pragma unroll
            for (int e = 0; e < 8; e++) p[e] = (short)f2bf(tl[og + e][orow]);
            *(bf16x8*)(Wtn + (size_t)(nt * 128 + orow) * K + kt * 64 + og) = p;
        }
    } else {
        const int flat = (blockIdx.x - TP_BLKS) * 256 + t;
        const int d8 = flat & 127;
        const int rem = flat >> 7;
        const int n = rem & 7;
        const int r = rem >> 3;
        const float* src = x + ((size_t)(cb + r) * NGRP + n) * DMODEL + d8 * 8;
        float4 v0 = *(const float4*)(src);
        float4 v1 = *(const float4*)(src + 4);
        bf16x8 p;
        p[0] = (short)f2bf(v0.x); p[1] = (short)f2bf(v0.y);
        p[2] = (short)f2bf(v0.z); p[3] = (short)f2bf(v0.w);
        p[4] = (short)f2bf(v1.x); p[5] = (short)f2bf(v1.y);
        p[6] = (short)f2bf(v1.z); p[7] = (short)f2bf(v1.w);
        *(bf16x8*)(xb + ((size_t)n * CH + r) * DMODEL + d8 * 8) = p;
    }
}

// ---- x-only conversion (chunks after the first, if CH < BTOT) ----
__global__ void conv_x(const float* __restrict__ x, ushort* __restrict__ xb,
                       int CH, int cb)
{
    const int flat = blockIdx.x * 256 + threadIdx.x;
    const int d8 = flat & 127;
    const int rem = flat >> 7;
    const int n = rem & 7;
    const int r = rem >> 3;
    const float* src = x + ((size_t)(cb + r) * NGRP + n) * DMODEL + d8 * 8;
    float4 v0 = *(const float4*)(src);
    float4 v1 = *(const float4*)(src + 4);
    bf16x8 p;
    p[0] = (short)f2bf(v0.x); p[1] = (short)f2bf(v0.y);
    p[2] = (short)f2bf(v0.z); p[3] = (short)f2bf(v0.w);
    p[4] = (short)f2bf(v1.x); p[5] = (short)f2bf(v1.y);
    p[6] = (short)f2bf(v1.z); p[7] = (short)f2bf(v1.w);
    *(bf16x8*)(xb + ((size_t)n * CH + r) * DMODEL + d8 * 8) = p;
}

// region(buf,op,half,ks): 128 rows x 32 k bf16 = 8 KiB, swizzled granules
#define REGN(buf,op,half,ks) (sm + ((((buf)*2+(op))*2+(half))*2+(ks))*4096)

template<int MH>
__device__ __forceinline__ void mma_q(f32x4 (&acc)[8][4], const bf16x8 (&af)[4],
                                      const bf16x8 (&bv)[4])
{
#pragma unroll
    for (int m4 = 0; m4 < 4; ++m4)
#pragma unroll
        for (int nf = 0; nf < 4; ++nf)
            acc[MH * 4 + m4][nf] = __builtin_amdgcn_mfma_f32_16x16x32_bf16(
                af[m4], bv[nf], acc[MH * 4 + m4][nf], 0, 0, 0);
}

// ---- 256x256 8-phase GEMM1 with 1-deep fragment pipeline (R4, frozen) ----
__global__ __launch_bounds__(512, 2)
void gemm8_1(const ushort* __restrict__ A, const ushort* __restrict__ Bt,
             const float* __restrict__ bias, ushort* __restrict__ h, int CH)
{
    constexpr int K = DMODEL, NDIM = HIDDEN, KT = K / 64;
    const int MT = CH >> 8, NT = NDIM >> 8;     // NT = 8
    extern __shared__ ushort sm[];

    const int nwg = gridDim.x;
    const int bid = blockIdx.x;
    const int swz = (bid & 7) * (nwg >> 3) + (bid >> 3);
    const int n   = swz / (MT * NT);
    const int rem = swz - n * (MT * NT);
    const int mt  = rem / NT;
    const int nt  = rem - mt * NT;

    const int tid = threadIdx.x;
    const int l = tid & 63, wid = tid >> 6;
    const int wr = wid >> 2, wc = wid & 3, wc2 = wc >> 1;
    const int lq = l >> 4, lr = l & 15;

    const ushort* Ab = A  + ((size_t)n * CH   + (size_t)mt * 256) * K;
    const ushort* Bb = Bt + ((size_t)n * NDIM + (size_t)nt * 256) * K;

    const int srow = tid >> 2;
    const int sseg = (tid & 3) ^ ((tid >> 3) & 3);

    auto stageA = [&](int b, int T, int ks) {
        const size_t kofs = (size_t)T * 64 + ks * 32 + sseg * 8;
        gl_lds16(Ab + (size_t)srow * K + kofs,         REGN(b, 0, 0, ks) + tid * 8);
        gl_lds16(Ab + (size_t)(128 + srow) * K + kofs, REGN(b, 0, 1, ks) + tid * 8);
    };
    auto stageB = [&](int b, int T, int ks) {
        const size_t kofs = (size_t)T * 64 + ks * 32 + sseg * 8;
        gl_lds16(Bb + (size_t)srow * K + kofs,         REGN(b, 1, 0, ks) + tid * 8);
        gl_lds16(Bb + (size_t)(128 + srow) * K + kofs, REGN(b, 1, 1, ks) + tid * 8);
    };
    auto ldA = [&](bf16x8 (&af)[4], int b, int kk, int mh) {
#pragma unroll
        for (int m4 = 0; m4 < 4; ++m4) {
            const int rh = mh * 64 + m4 * 16 + lr;
            af[m4] = *(const bf16x8*)(REGN(b, 0, wr, kk) + rh * 32 + (lq ^ ((rh >> 1) & 3)) * 8);
        }
    };
    auto ldB = [&](bf16x8 (&bv)[4], int b, int kk) {
#pragma unroll
        for (int nf = 0; nf < 4; ++nf) {
            const int rb = (wc & 1) * 64 + nf * 16 + lr;
            bv[nf] = *(const bf16x8*)(REGN(b, 1, wc2, kk) + rb * 32 + (lq ^ ((rb >> 1) & 3)) * 8);
        }
    };

    f32x4 acc[8][4];
#pragma unroll
    for (int i = 0; i < 8; ++i)
#pragma unroll
        for (int j = 0; j < 4; ++j) acc[i][j] = (f32x4){0.f, 0.f, 0.f, 0.f};

    stageA(0, 0, 0); stageB(0, 0, 0); stageA(0, 0, 1); stageB(0, 0, 1);
    asm volatile("s_waitcnt vmcnt(4)" ::: "memory");
    __builtin_amdgcn_s_barrier();

    bf16x8 aX[4], aY[4], bv0[4], bv1[4];
    ldA(aX, 0, 0, 0); ldB(bv0, 0, 0);

    for (int g = 0; g < KT; ++g) {
        const int c = g & 1;
        const bool ns = (g + 1 < KT);

        ldA(aY, c, 0, 1);
        if (ns) stageA(c ^ 1, g + 1, 0);
        asm volatile("s_waitcnt lgkmcnt(4)" ::: "memory");
        __builtin_amdgcn_sched_barrier(0);
        __builtin_amdgcn_s_setprio(1);
        mma_q<0>(acc, aX, bv0);
        __builtin_amdgcn_s_setprio(0);
        if (ns) asm volatile("s_waitcnt vmcnt(2)" ::: "memory");
        else    asm volatile("s_waitcnt vmcnt(0)" ::: "memory");
        __builtin_amdgcn_s_barrier();

        ldA(aX, c, 1, 0); ldB(bv1, c, 1);
        if (ns) stageB(c ^ 1, g + 1, 0);
        asm volatile("s_waitcnt lgkmcnt(8)" ::: "memory");
        __builtin_amdgcn_sched_barrier(0);
        __builtin_amdgcn_s_setprio(1);
        mma_q<1>(acc, aY, bv0);
        __builtin_amdgcn_s_setprio(0);
        __builtin_amdgcn_s_barrier();

        ldA(aY, c, 1, 1);
        if (ns) stageA(c ^ 1, g + 1, 1);
        asm volatile("s_waitcnt lgkmcnt(4)" ::: "memory");
        __builtin_amdgcn_sched_barrier(0);
        __builtin_amdgcn_s_setprio(1);
        mma_q<0>(acc, aX, bv1);
        __builtin_amdgcn_s_setprio(0);
        __builtin_amdgcn_s_barrier();

        if (ns) stageB(c ^ 1, g + 1, 1);
        asm volatile("s_waitcnt lgkmcnt(0)" ::: "memory");
        __builtin_amdgcn_sched_barrier(0);
        __builtin_amdgcn_s_setprio(1);
        mma_q<1>(acc, aY, bv1);
        __builtin_amdgcn_s_setprio(0);
        if (ns) asm volatile("s_waitcnt vmcnt(4)" ::: "memory");
        __builtin_amdgcn_s_barrier();
        if (ns) { ldA(aX, c ^ 1, 0, 0); ldB(bv0, c ^ 1, 0); }
    }

    __builtin_amdgcn_sched_barrier(0);

    float bias4[4];
#pragma unroll
    for (int nf = 0; nf < 4; ++nf)
        bias4[nf] = bias[(size_t)n * NDIM + nt * 256 + wc * 64 + nf * 16 + lr];
#pragma unroll
    for (int m = 0; m < 8; ++m) {
#pragma unroll
        for (int r = 0; r < 4; ++r) {
            const int row = mt * 256 + wr * 128 + m * 16 + lq * 4 + r;
            ushort* dst = h + ((size_t)n * CH + row) * HIDDEN + nt * 256 + wc * 64 + lr;
#pragma unroll
            for (int nf = 0; nf < 4; ++nf)
                dst[nf * 16] = f2bf(fmaxf(acc[m][nf][r] + bias4[nf], 0.f));
        }
    }
}

// ---- GEMM2 64x256 dbuf + counted vmcnt + XCD-swizzle (T1): out = h@W2t^T + b2 ----
// grid flattened 1D = MT2*NGRP; XCD x owns one n-group -> W2t panel (1 MB) L2-resident
__global__ __launch_bounds__(256, 2)
void gemm2w(const ushort* __restrict__ A, const ushort* __restrict__ Bt,
            const float* __restrict__ bias, float* __restrict__ outp,
            int CH, int cb)
{
    constexpr int K = HIDDEN, BK = 64, KT = K / BK;
    constexpr int BUFSZ = (64 + 256) * BK;
    extern __shared__ ushort sm2[];

    const int nwg = gridDim.x;                  // MT2 * NGRP, divisible by 8
    const int bid = blockIdx.x;
    const int swz = (bid & 7) * (nwg >> 3) + (bid >> 3);
    const int MT2 = CH >> 6;
    const int n  = swz / MT2;
    const int mt = swz - n * MT2;

    const ushort* Ab = A  + ((size_t)n * CH + mt * 64) * K;
    const ushort* Bb = Bt + (size_t)n * ABIN * K;

    const int t = threadIdx.x, l = t & 63, w = t >> 6;
    const int wr = w >> 1, wc = w & 1;
    const int lq = l >> 4, lr = l & 15;

    auto stage = [&](int b, int ki) {
        ushort* As = sm2 + b * BUFSZ;
        ushort* Bs = As + 64 * BK;
        const ushort* Ak = Ab + ki * BK;
        const ushort* Bk = Bb + ki * BK;
#pragma unroll
        for (int i = 0; i < 2; i++) {
            const int flat = t + 256 * i;
            const int row = flat >> 3;
            const int seg = (flat & 7) ^ (row & 7);
            gl_lds16(Ak + (size_t)row * K + seg * 8, As + flat * 8);
        }
#pragma unroll
        for (int i = 0; i < 8; i++) {
            const int flat = t + 256 * i;
            const int row = flat >> 3;
            const int seg = (flat & 7) ^ (row & 7);
            gl_lds16(Bk + (size_t)row * K + seg * 8, Bs + flat * 8);
        }
    };

    f32x4 acc[2][8];
#pragma unroll
    for (int i = 0; i < 2; i++)
#pragma unroll
        for (int j = 0; j < 8; j++) acc[i][j] = (f32x4){0.f, 0.f, 0.f, 0.f};

    stage(0, 0);

    for (int ki = 0; ki < KT; ++ki) {
        const int c = ki & 1;
        if (ki + 1 < KT) {
            stage(c ^ 1, ki + 1);
            asm volatile("s_waitcnt vmcnt(10)" ::: "memory");
        } else {
            asm volatile("s_waitcnt vmcnt(0)" ::: "memory");
        }
        __builtin_amdgcn_s_barrier();
        __builtin_amdgcn_sched_barrier(0);

        const ushort* As = sm2 + c * BUFSZ;
        const ushort* Bs = As + 64 * BK;
#pragma unroll
        for (int kk = 0; kk < 2; kk++) {
            bf16x8 af[2], bf[8];
#pragma unroll
            for (int m = 0; m < 2; m++) {
                const int row = wr * 32 + m * 16 + lr;
                af[m] = *(const bf16x8*)&As[row * BK + ((kk * 4 + lq) ^ (row & 7)) * 8];
            }
#pragma unroll
            for (int nf = 0; nf < 8; nf++) {
                const int row = wc * 128 + nf * 16 + lr;
                bf[nf] = *(const bf16x8*)&Bs[row * BK + ((kk * 4 + lq) ^ (row & 7)) * 8];
            }
#pragma unroll
            for (int m = 0; m < 2; m++)
#pragma unroll
                for (int nf = 0; nf < 8; nf++)
                    acc[m][nf] = __builtin_amdgcn_mfma_f32_16x16x32_bf16(af[m], bf[nf], acc[m][nf], 0, 0, 0);
        }
        __builtin_amdgcn_s_barrier();
    }

    float bias8[8];
#pragma unroll
    for (int nf = 0; nf < 8; nf++)
        bias8[nf] = bias[(size_t)n * ABIN + wc * 128 + nf * 16 + lr];
#pragma unroll
    for (int m = 0; m < 2; m++) {
#pragma unroll
        for (int r = 0; r < 4; r++) {
            const int row = mt * 64 + wr * 32 + m * 16 + lq * 4 + r;
            float* dst = outp + ((size_t)(cb + row) * NGRP + n) * ABIN + wc * 128 + lr;
#pragma unroll
            for (int nf = 0; nf < 8; nf++)
                dst[nf * 16] = acc[m][nf][r] + bias8[nf];
        }
    }
}

extern "C" void kernel_launch(void* const* d_in, const int* in_sizes, int n_in,
                              void* d_out, int out_size, void* d_ws, size_t ws_size,
                              hipStream_t stream)
{
    const float* x  = (const float*)d_in[0];
    const float* W1 = (const float*)d_in[1];
    const float* b1 = (const float*)d_in[2];
    const float* W2 = (const float*)d_in[3];
    const float* b2 = (const float*)d_in[4];

    hipFuncSetAttribute((const void*)gemm8_1,
                        hipFuncAttributeMaxDynamicSharedMemorySize, 131072);
    hipFuncSetAttribute((const void*)gemm2w,
                        hipFuncAttributeMaxDynamicSharedMemorySize, 81920);

    ushort* W1t = (ushort*)d_ws;                              // [8][2048][1024]
    ushort* W2t = W1t + (size_t)NGRP * HIDDEN * DMODEL;       // [8][256][2048]
    ushort* xb  = W2t + (size_t)NGRP * ABIN * HIDDEN;
    const size_t fixed = ((size_t)NGRP * HIDDEN * DMODEL + (size_t)NGRP * ABIN * HIDDEN) * 2;

    int CH = 4096;
    while (CH > 256 && fixed + (size_t)CH * (NGRP * (DMODEL + HIDDEN) * 2) > ws_size) CH >>= 1;
    ushort* h = xb + (size_t)NGRP * CH * DMODEL;

    // chunk 0: fused transpose(W1,W2) + conv(x chunk 0)
    prep<<<TP_BLKS + CH * 4, 256, 0, stream>>>(W1, W1t, W2, W2t, x, xb, CH, 0);

    for (int cb = 0; cb < BTOT; cb += CH) {
        if (cb > 0)
            conv_x<<<CH * 4, 256, 0, stream>>>(x, xb, CH, cb);
        const int g1 = NGRP * (CH / 256) * (HIDDEN / 256);
        gemm8_1<<<g1, 512, 131072, stream>>>(xb, W1t, b1, h, CH);
        gemm2w<<<(CH / 64) * NGRP, 256, 81920, stream>>>(h, W2t, b2, (float*)d_out, CH, cb);
    }
}